// Round 3
// baseline (347.871 us; speedup 1.0000x reference)
//
#include <hip/hip_runtime.h>
#include <hip/hip_bf16.h>

typedef __attribute__((ext_vector_type(8))) __bf16 bf16x8;
typedef __attribute__((ext_vector_type(8))) unsigned short u16x8;
typedef __attribute__((ext_vector_type(4))) float f32x4;

#define BATCH 16
#define CH    64
#define NN    65536
#define BKE   128               // K floats per tile in k_energy
#define KCHUNK 2048             // K per block
#define NT    (KCHUNK / BKE)    // 16 tiles
#define NC    (NN / KCHUNK)     // 32 chunks per batch
#define TILEB (CH * BKE * 4)    // 32 KiB per tile
#define NB    256

__device__ __forceinline__ unsigned short f2bf(float f) {
  unsigned int u = __float_as_uint(f);
  u += 0x7FFFu + ((u >> 16) & 1u);   // RNE
  return (unsigned short)(u >> 16);
}

__global__ __launch_bounds__(256) void k_zero(float* p) {
  p[blockIdx.x * 256 + threadIdx.x] = 0.0f;
}

// Pass 1: energy[b,i,j] = sum_n x[b,i,n] x[b,j,n], split-K.
// v3: async global_load_lds (width=16) + 2-tile double-buffer (T3-min).
// LDS holds raw fp32, XOR-preswizzled on the GLOBAL source side (rule #21):
//   LDS[row][cg] (16B granule) = G[row][cg ^ (row&7)]
// Fragment reads apply the same involution; bf16 convert happens on read.
template <bool ATOMIC>
__global__ __launch_bounds__(256) void k_energy(const float* __restrict__ x,
                                                float* __restrict__ dst) {
  const int chunk = blockIdx.x;          // 0..NC-1
  const int b = blockIdx.y;              // 0..15
  const int t = threadIdx.x;
  const int w = t >> 6;                  // wave 0..3
  const int lane = t & 63;
  const int fr = lane & 15;
  const int grp = lane >> 4;

  __shared__ __align__(16) float xs[2 * CH * BKE];   // 64 KiB double-buffer

  f32x4 acc[4] = {};
  const float* xb = x + (size_t)b * CH * NN;
  const int k0 = chunk * KCHUNK;

  auto stage = [&](int buf, int tile) {
    const int kb = k0 + tile * BKE;
    char* ldsbase = ((char*)xs) + buf * TILEB;
    #pragma unroll
    for (int i = 0; i < 8; ++i) {              // 2048 granules / 256 threads
      const int g = i * 256 + t;
      const int row = g >> 5;                  // 32 granules per 512B row
      const int cg = g & 31;
      const float* src = xb + (size_t)row * NN + kb + ((cg ^ (row & 7)) << 2);
      __builtin_amdgcn_global_load_lds(
          (const __attribute__((address_space(1))) void*)src,
          (__attribute__((address_space(3))) void*)(ldsbase + (i * 256 + w * 64) * 16),
          16, 0, 0);
    }
  };

  auto compute = [&](int buf) {
    const char* base = ((const char*)xs) + buf * TILEB;
    #pragma unroll
    for (int kk = 0; kk < BKE / 32; ++kk) {    // 4 k-steps of 32
      bf16x8 bf[4];
      #pragma unroll
      for (int tt = 0; tt < 4; ++tt) {
        const int r = tt * 16 + fr;
        const int cb = kk * 128 + grp * 32;
        const int m = (r & 7) << 4;
        const f32x4 u0 = *(const f32x4*)(base + r * 512 + (cb ^ m));
        const f32x4 u1 = *(const f32x4*)(base + r * 512 + ((cb + 16) ^ m));
        u16x8 pk;
        pk[0] = f2bf(u0[0]); pk[1] = f2bf(u0[1]); pk[2] = f2bf(u0[2]); pk[3] = f2bf(u0[3]);
        pk[4] = f2bf(u1[0]); pk[5] = f2bf(u1[1]); pk[6] = f2bf(u1[2]); pk[7] = f2bf(u1[3]);
        bf[tt] = *(bf16x8*)&pk;
      }
      const bf16x8 af = bf[w];                 // A rows == B rows for tt==w
      #pragma unroll
      for (int tt = 0; tt < 4; ++tt)
        acc[tt] = __builtin_amdgcn_mfma_f32_16x16x32_bf16(af, bf[tt], acc[tt], 0, 0, 0);
    }
  };

  stage(0, 0);
  __syncthreads();
  int buf = 0;
  for (int tile = 0; tile < NT; ++tile) {
    if (tile + 1 < NT) stage(buf ^ 1, tile + 1);  // async, overlaps compute
    compute(buf);
    __syncthreads();                               // vmcnt0+lgkm0+barrier
    buf ^= 1;
  }

  // C/D layout (m89-verified): col = lane&15, row = (lane>>4)*4 + reg
  #pragma unroll
  for (int tt = 0; tt < 4; ++tt) {
    #pragma unroll
    for (int r = 0; r < 4; ++r) {
      const int i = w * 16 + grp * 4 + r;
      const int j = tt * 16 + fr;
      if (ATOMIC) {
        atomicAdd(&dst[((size_t)b * CH + i) * CH + j], acc[tt][r]);
      } else {
        float* p = dst + ((size_t)b * NC + chunk) * (CH * CH);
        p[i * CH + j] = acc[tt][r];
      }
    }
  }
}

// Fused reduce(+softmax): block (i,b), thread j sums NC partials (coalesced),
// wave-wide min/sum via shfl_xor. softmax(rowmax-e) = exp(minE-e)/sum.
// Writes TRANSPOSED attn_t[b][j][i].
__global__ __launch_bounds__(64) void k_redsm(const float* __restrict__ partial,
                                              float* __restrict__ attn_t) {
  const int i = blockIdx.x;
  const int b = blockIdx.y;
  const int j = threadIdx.x;
  const float* p = partial + (size_t)b * NC * (CH * CH) + i * CH + j;
  float e = 0.0f;
  #pragma unroll 8
  for (int c = 0; c < NC; ++c) e += p[(size_t)c * (CH * CH)];
  float mn = e;
  #pragma unroll
  for (int off = 32; off; off >>= 1) mn = fminf(mn, __shfl_xor(mn, off, 64));
  const float v = __expf(mn - e);
  float sum = v;
  #pragma unroll
  for (int off = 32; off; off >>= 1) sum += __shfl_xor(sum, off, 64);
  attn_t[(size_t)b * (CH * CH) + j * CH + i] = v / sum;
}

// Fallback softmax (atomic path): reads dense energy.
__global__ __launch_bounds__(64) void k_softmax(const float* __restrict__ energy,
                                                float* __restrict__ attn_t) {
  const int b = blockIdx.x;
  const int i = threadIdx.x;
  const float* e = energy + ((size_t)b * CH + i) * CH;
  float ev[CH];
  float mn = 3.402823466e38f;
  #pragma unroll
  for (int j = 0; j < CH; ++j) { ev[j] = e[j]; mn = fminf(mn, ev[j]); }
  float sum = 0.0f;
  #pragma unroll
  for (int j = 0; j < CH; ++j) { ev[j] = __expf(mn - ev[j]); sum += ev[j]; }
  const float inv = 1.0f / sum;
  #pragma unroll
  for (int j = 0; j < CH; ++j) attn_t[((size_t)b * CH + j) * CH + i] = ev[j] * inv;
}

// Pass 3: out[b,i,n] = gamma * sum_j attn[i,j] x[b,j,n] + x[b,i,n], fp32.
// At its memory floor (~512 MB @ ~6.6 TB/s) — unchanged.
__global__ __launch_bounds__(256) void k_out(const float* __restrict__ x,
                                             const float* __restrict__ attn_t,
                                             const float* __restrict__ gamma,
                                             float* __restrict__ out) {
  const int b = blockIdx.y;
  const int n0 = blockIdx.x * NB;
  const int t = threadIdx.x;
  const int w = t >> 6;
  const int lane = t & 63;

  __shared__ __align__(16) float xsh[CH * NB];  // 64 KiB
  __shared__ __align__(16) float ash[CH * CH];  // 16 KiB

  const float* xb = x + (size_t)b * CH * NN;
  #pragma unroll
  for (int it = 0; it < 16; ++it) {
    const int flat = it * 256 + t;
    const int row = flat >> 6;
    const int c4 = flat & 63;
    *reinterpret_cast<f32x4*>(&xsh[row * NB + c4 * 4]) =
        *reinterpret_cast<const f32x4*>(xb + (size_t)row * NN + n0 + c4 * 4);
  }
  #pragma unroll
  for (int it = 0; it < 4; ++it) {
    const int flat = it * 256 + t;
    *reinterpret_cast<f32x4*>(&ash[flat * 4]) =
        *reinterpret_cast<const f32x4*>(attn_t + (size_t)b * CH * CH + flat * 4);
  }
  const float g = gamma[0];
  __syncthreads();

  f32x4 acc[16] = {};
  #pragma unroll 4
  for (int j = 0; j < CH; ++j) {
    const f32x4 xv = *reinterpret_cast<const f32x4*>(&xsh[j * NB + lane * 4]);
    #pragma unroll
    for (int q = 0; q < 4; ++q) {
      const f32x4 av = *reinterpret_cast<const f32x4*>(&ash[j * CH + w * 16 + q * 4]);
      acc[q * 4 + 0] += av[0] * xv;
      acc[q * 4 + 1] += av[1] * xv;
      acc[q * 4 + 2] += av[2] * xv;
      acc[q * 4 + 3] += av[3] * xv;
    }
  }
  float* ob = out + (size_t)b * CH * NN;
  #pragma unroll
  for (int r = 0; r < 16; ++r) {
    const int i = w * 16 + r;
    const f32x4 xv = *reinterpret_cast<const f32x4*>(&xsh[i * NB + lane * 4]);
    const f32x4 o = g * acc[r] + xv;  // exact fp32 epilogue
    *reinterpret_cast<f32x4*>(ob + (size_t)i * NN + n0 + lane * 4) = o;
  }
}

extern "C" void kernel_launch(void* const* d_in, const int* in_sizes, int n_in,
                              void* d_out, int out_size, void* d_ws, size_t ws_size,
                              hipStream_t stream) {
  const float* x = (const float*)d_in[0];
  const float* gamma = (const float*)d_in[1];
  float* out = (float*)d_out;

  const size_t part_elems = (size_t)BATCH * NC * CH * CH;   // 2M floats = 8.4 MB
  const size_t attn_elems = (size_t)BATCH * CH * CH;
  const size_t need = (part_elems + attn_elems) * sizeof(float);

  if (ws_size >= need) {
    float* partial = (float*)d_ws;
    float* attn_t = partial + part_elems;
    k_energy<false><<<dim3(NC, BATCH), 256, 0, stream>>>(x, partial);
    k_redsm<<<dim3(CH, BATCH), 64, 0, stream>>>(partial, attn_t);
    k_out<<<dim3(NN / NB, BATCH), 256, 0, stream>>>(x, attn_t, gamma, out);
  } else {
    float* energy = (float*)d_ws;
    float* attn_t = energy + attn_elems;
    k_zero<<<dim3((BATCH * CH * CH) / 256), 256, 0, stream>>>(energy);
    k_energy<true><<<dim3(NC, BATCH), 256, 0, stream>>>(x, energy);
    k_softmax<<<dim3(BATCH), 64, 0, stream>>>(energy, attn_t);
    k_out<<<dim3(NN / NB, BATCH), 256, 0, stream>>>(x, attn_t, gamma, out);
  }
}

// Round 4
// 339.907 us; speedup vs baseline: 1.0234x; 1.0234x over previous
//
#include <hip/hip_runtime.h>
#include <hip/hip_bf16.h>

typedef __attribute__((ext_vector_type(8))) __bf16 bf16x8;
typedef __attribute__((ext_vector_type(4))) float f32x4;

#define BATCH 16
#define CH    64
#define NN    65536
#define BKE   128               // K floats per tile
#define KCHUNK 2048             // K per block
#define NT    (KCHUNK / BKE)    // 16 tiles
#define NC    (NN / KCHUNK)     // 32 chunks per batch
#define NB    256

__device__ __forceinline__ unsigned short f2bf(float f) {
  unsigned int u = __float_as_uint(f);
  u += 0x7FFFu + ((u >> 16) & 1u);   // RNE
  return (unsigned short)(u >> 16);
}

__global__ __launch_bounds__(256) void k_zero(float* p) {
  p[blockIdx.x * 256 + threadIdx.x] = 0.0f;
}

// Pass 1: energy[b,i,j] = sum_n x[b,i,n] x[b,j,n], split-K.
// v4 pipeline per 64x128 tile:
//   (1) global_load_lds fp32 -> linear LDS s32 (double-buffered, async)
//   (2) thread-sliced convert: s32 -> bf16 s16 (XOR-swizzled), ONCE per element
//   (3) MFMA from s16 (fragment reads 2-way conflicts = free)
// Mid-tile barrier is raw s_barrier + lgkmcnt(0) only -> next tile's DMA
// stays in flight through convert+MFMA; __syncthreads at tile end drains it.
template <bool ATOMIC>
__global__ __launch_bounds__(256) void k_energy(const float* __restrict__ x,
                                                float* __restrict__ dst) {
  const int chunk = blockIdx.x;          // 0..NC-1
  const int b = blockIdx.y;              // 0..15
  const int t = threadIdx.x;
  const int w = t >> 6;                  // wave 0..3
  const int lane = t & 63;
  const int fr = lane & 15;
  const int grp = lane >> 4;

  __shared__ __align__(16) float s32[2][CH * BKE];        // 2 x 32 KiB, linear
  __shared__ __align__(16) unsigned short s16[CH * BKE];  // 16 KiB, swizzled

  f32x4 acc[4] = {};
  const float* xb = x + (size_t)b * CH * NN;
  const int k0 = chunk * KCHUNK;

  auto stage = [&](int buf, int tile) {
    const int kb = k0 + tile * BKE;
    char* ldsbase = (char*)&s32[buf][0];
    #pragma unroll
    for (int i = 0; i < 8; ++i) {        // 2048 granules of 16B / 256 threads
      const int g = i * 256 + t;
      const int row = g >> 5;            // 32 granules per 512B row
      const int cg = g & 31;
      const float* src = xb + (size_t)row * NN + kb + cg * 4;
      __builtin_amdgcn_global_load_lds(
          (const __attribute__((address_space(1))) void*)src,
          (__attribute__((address_space(3))) void*)(ldsbase + g * 16),
          16, 0, 0);                     // dest = wave-uniform base + lane*16
    }
  };

  auto convert = [&](int buf) {
    #pragma unroll
    for (int i = 0; i < 8; ++i) {
      const int g = i * 256 + t;         // stride-1 granules: conflict-free
      const int row = g >> 5;
      const int cg = g & 31;
      const f32x4 v = *(const f32x4*)((const char*)&s32[buf][0] + (size_t)g * 16);
      ushort4 pk;
      pk.x = f2bf(v[0]); pk.y = f2bf(v[1]); pk.z = f2bf(v[2]); pk.w = f2bf(v[3]);
      int byte = row * 256 + cg * 8;     // bf16 row = 256B
      byte ^= (row & 7) << 4;            // XOR swizzle (G4)
      *(ushort4*)((char*)s16 + byte) = pk;
    }
  };

  auto mfma_tile = [&]() {
    const char* base = (const char*)s16;
    #pragma unroll
    for (int kk = 0; kk < BKE / 32; ++kk) {
      bf16x8 bfr[4];
      #pragma unroll
      for (int tt = 0; tt < 4; ++tt) {
        const int row = tt * 16 + fr;
        const int colb = kk * 64 + grp * 16;
        const int off = row * 256 + (colb ^ ((row & 7) << 4));
        bfr[tt] = *(const bf16x8*)(base + off);   // 2-way conflict = free
      }
      const bf16x8 af = bfr[w];                   // A rows == B rows for tt==w
      #pragma unroll
      for (int tt = 0; tt < 4; ++tt)
        acc[tt] = __builtin_amdgcn_mfma_f32_16x16x32_bf16(af, bfr[tt], acc[tt], 0, 0, 0);
    }
  };

  stage(0, 0);
  __syncthreads();                       // drain DMA(0)
  int cur = 0;
  for (int tile = 0; tile < NT; ++tile) {
    if (tile + 1 < NT) stage(cur ^ 1, tile + 1);  // async: flies through cvt+MFMA
    convert(cur);
    // bf16 tile ready: wait own ds_writes, barrier — do NOT drain vmcnt
    asm volatile("s_waitcnt lgkmcnt(0)" ::: "memory");
    __builtin_amdgcn_sched_barrier(0);
    __builtin_amdgcn_s_barrier();
    __builtin_amdgcn_sched_barrier(0);
    mfma_tile();
    __syncthreads();   // drains vmcnt(0): DMA(t+1) landed; all s16 reads done
    cur ^= 1;
  }

  // C/D layout (m89-verified): col = lane&15, row = (lane>>4)*4 + reg
  #pragma unroll
  for (int tt = 0; tt < 4; ++tt) {
    #pragma unroll
    for (int r = 0; r < 4; ++r) {
      const int i = w * 16 + grp * 4 + r;
      const int j = tt * 16 + fr;
      if (ATOMIC) {
        atomicAdd(&dst[((size_t)b * CH + i) * CH + j], acc[tt][r]);
      } else {
        float* p = dst + ((size_t)b * NC + chunk) * (CH * CH);
        p[i * CH + j] = acc[tt][r];
      }
    }
  }
}

// Fused reduce(+softmax): block (i,b), thread j sums NC partials (coalesced),
// wave-wide min/sum via shfl_xor. softmax(rowmax-e) = exp(minE-e)/sum.
// Writes TRANSPOSED attn_t[b][j][i].
__global__ __launch_bounds__(64) void k_redsm(const float* __restrict__ partial,
                                              float* __restrict__ attn_t) {
  const int i = blockIdx.x;
  const int b = blockIdx.y;
  const int j = threadIdx.x;
  const float* p = partial + (size_t)b * NC * (CH * CH) + i * CH + j;
  float e = 0.0f;
  #pragma unroll 8
  for (int c = 0; c < NC; ++c) e += p[(size_t)c * (CH * CH)];
  float mn = e;
  #pragma unroll
  for (int off = 32; off; off >>= 1) mn = fminf(mn, __shfl_xor(mn, off, 64));
  const float v = __expf(mn - e);
  float sum = v;
  #pragma unroll
  for (int off = 32; off; off >>= 1) sum += __shfl_xor(sum, off, 64);
  attn_t[(size_t)b * (CH * CH) + j * CH + i] = v / sum;
}

// Fallback softmax (atomic path): reads dense energy.
__global__ __launch_bounds__(64) void k_softmax(const float* __restrict__ energy,
                                                float* __restrict__ attn_t) {
  const int b = blockIdx.x;
  const int i = threadIdx.x;
  const float* e = energy + ((size_t)b * CH + i) * CH;
  float ev[CH];
  float mn = 3.402823466e38f;
  #pragma unroll
  for (int j = 0; j < CH; ++j) { ev[j] = e[j]; mn = fminf(mn, ev[j]); }
  float sum = 0.0f;
  #pragma unroll
  for (int j = 0; j < CH; ++j) { ev[j] = __expf(mn - ev[j]); sum += ev[j]; }
  const float inv = 1.0f / sum;
  #pragma unroll
  for (int j = 0; j < CH; ++j) attn_t[((size_t)b * CH + j) * CH + i] = ev[j] * inv;
}

// Pass 3: out[b,i,n] = gamma * sum_j attn[i,j] x[b,j,n] + x[b,i,n], fp32.
// ~6.7 TB/s vs 7.0 achievable — at floor, unchanged.
__global__ __launch_bounds__(256) void k_out(const float* __restrict__ x,
                                             const float* __restrict__ attn_t,
                                             const float* __restrict__ gamma,
                                             float* __restrict__ out) {
  const int b = blockIdx.y;
  const int n0 = blockIdx.x * NB;
  const int t = threadIdx.x;
  const int w = t >> 6;
  const int lane = t & 63;

  __shared__ __align__(16) float xsh[CH * NB];  // 64 KiB
  __shared__ __align__(16) float ash[CH * CH];  // 16 KiB

  const float* xb = x + (size_t)b * CH * NN;
  #pragma unroll
  for (int it = 0; it < 16; ++it) {
    const int flat = it * 256 + t;
    const int row = flat >> 6;
    const int c4 = flat & 63;
    *reinterpret_cast<f32x4*>(&xsh[row * NB + c4 * 4]) =
        *reinterpret_cast<const f32x4*>(xb + (size_t)row * NN + n0 + c4 * 4);
  }
  #pragma unroll
  for (int it = 0; it < 4; ++it) {
    const int flat = it * 256 + t;
    *reinterpret_cast<f32x4*>(&ash[flat * 4]) =
        *reinterpret_cast<const f32x4*>(attn_t + (size_t)b * CH * CH + flat * 4);
  }
  const float g = gamma[0];
  __syncthreads();

  f32x4 acc[16] = {};
  #pragma unroll 4
  for (int j = 0; j < CH; ++j) {
    const f32x4 xv = *reinterpret_cast<const f32x4*>(&xsh[j * NB + lane * 4]);
    #pragma unroll
    for (int q = 0; q < 4; ++q) {
      const f32x4 av = *reinterpret_cast<const f32x4*>(&ash[j * CH + w * 16 + q * 4]);
      acc[q * 4 + 0] += av[0] * xv;
      acc[q * 4 + 1] += av[1] * xv;
      acc[q * 4 + 2] += av[2] * xv;
      acc[q * 4 + 3] += av[3] * xv;
    }
  }
  float* ob = out + (size_t)b * CH * NN;
  #pragma unroll
  for (int r = 0; r < 16; ++r) {
    const int i = w * 16 + r;
    const f32x4 xv = *reinterpret_cast<const f32x4*>(&xsh[i * NB + lane * 4]);
    const f32x4 o = g * acc[r] + xv;  // exact fp32 epilogue
    *reinterpret_cast<f32x4*>(ob + (size_t)i * NN + n0 + lane * 4) = o;
  }
}

extern "C" void kernel_launch(void* const* d_in, const int* in_sizes, int n_in,
                              void* d_out, int out_size, void* d_ws, size_t ws_size,
                              hipStream_t stream) {
  const float* x = (const float*)d_in[0];
  const float* gamma = (const float*)d_in[1];
  float* out = (float*)d_out;

  const size_t part_elems = (size_t)BATCH * NC * CH * CH;   // 2M floats = 8.4 MB
  const size_t attn_elems = (size_t)BATCH * CH * CH;
  const size_t need = (part_elems + attn_elems) * sizeof(float);

  if (ws_size >= need) {
    float* partial = (float*)d_ws;
    float* attn_t = partial + part_elems;
    k_energy<false><<<dim3(NC, BATCH), 256, 0, stream>>>(x, partial);
    k_redsm<<<dim3(CH, BATCH), 64, 0, stream>>>(partial, attn_t);
    k_out<<<dim3(NN / NB, BATCH), 256, 0, stream>>>(x, attn_t, gamma, out);
  } else {
    float* energy = (float*)d_ws;
    float* attn_t = energy + attn_elems;
    k_zero<<<dim3((BATCH * CH * CH) / 256), 256, 0, stream>>>(energy);
    k_energy<true><<<dim3(NC, BATCH), 256, 0, stream>>>(x, energy);
    k_softmax<<<dim3(BATCH), 64, 0, stream>>>(energy, attn_t);
    k_out<<<dim3(NN / NB, BATCH), 256, 0, stream>>>(x, attn_t, gamma, out);
  }
}